// Round 3
// baseline (702.731 us; speedup 1.0000x reference)
//
#include <hip/hip_runtime.h>
#include <math.h>

#define CIN 128
#define HD  96
#define SP  3136   // 56*56
#define ROW 56

// ---------------- Kernel 1: q/value 1x1 conv (fused) ----------------
__global__ __launch_bounds__(256) void qv_conv(
    const float* __restrict__ x, const float* __restrict__ Wc,
    const float* __restrict__ bc, const float* __restrict__ Wp,
    const float* __restrict__ bp, float* __restrict__ qbuf,
    float* __restrict__ vbuf)
{
  const int st = blockIdx.x % 49;
  const int b  = blockIdx.x / 49;
  const float* xb = x + (size_t)b * CIN * SP + st * 64;

  __shared__ float xs[32][64];
  __shared__ float wl[32][196];

  const int tid = threadIdx.x;
  const int og = tid >> 4;
  const int sg = tid & 15;

  float acc[12][4];
  #pragma unroll
  for (int i = 0; i < 12; ++i) { acc[i][0]=0.f; acc[i][1]=0.f; acc[i][2]=0.f; acc[i][3]=0.f; }

  for (int kt = 0; kt < 4; ++kt) {
    __syncthreads();
    #pragma unroll
    for (int r = 0; r < 2; ++r) {
      int i = tid + r * 256;
      int cc = i >> 4, s4 = i & 15;
      float4 v = *reinterpret_cast<const float4*>(xb + (size_t)(kt*32 + cc) * SP + s4*4);
      *reinterpret_cast<float4*>(&xs[cc][s4*4]) = v;
    }
    #pragma unroll
    for (int r = 0; r < 6; ++r) {
      int i = tid + r * 256;
      int o  = i >> 3, c4 = i & 7;
      const float* wrow = (o < 96) ? (Wc + (size_t)o * CIN) : (Wp + (size_t)(o - 96) * CIN);
      float4 wv = *reinterpret_cast<const float4*>(wrow + kt*32 + c4*4);
      wl[c4*4+0][o] = wv.x; wl[c4*4+1][o] = wv.y;
      wl[c4*4+2][o] = wv.z; wl[c4*4+3][o] = wv.w;
    }
    __syncthreads();
    #pragma unroll
    for (int cc = 0; cc < 32; ++cc) {
      float xv[4];
      *reinterpret_cast<float4*>(xv) = *reinterpret_cast<const float4*>(&xs[cc][sg*4]);
      float wv[12];
      *reinterpret_cast<float4*>(wv + 0) = *reinterpret_cast<const float4*>(&wl[cc][og*12 + 0]);
      *reinterpret_cast<float4*>(wv + 4) = *reinterpret_cast<const float4*>(&wl[cc][og*12 + 4]);
      *reinterpret_cast<float4*>(wv + 8) = *reinterpret_cast<const float4*>(&wl[cc][og*12 + 8]);
      #pragma unroll
      for (int i = 0; i < 12; ++i)
        #pragma unroll
        for (int j = 0; j < 4; ++j)
          acc[i][j] = fmaf(wv[i], xv[j], acc[i][j]);
    }
  }
  #pragma unroll
  for (int i = 0; i < 12; ++i) {
    int o = og * 12 + i;
    float bias; float* dst;
    if (o < 96) { bias = bc[o];      dst = qbuf + ((size_t)b*96 + o      ) * SP + st*64; }
    else        { bias = bp[o - 96]; dst = vbuf + ((size_t)b*96 + (o - 96)) * SP + st*64; }
    float4 v;
    v.x = acc[i][0] + bias; v.y = acc[i][1] + bias;
    v.z = acc[i][2] + bias; v.w = acc[i][3] + bias;
    *reinterpret_cast<float4*>(dst + sg*4) = v;
  }
}

// ---------------- Kernel 2: clustering, one 1024-thread block per (b,e) ----------------
// Handles all 4 folds of a 24-channel 56x56 plane; all HBM access full-line.
__global__ __launch_bounds__(1024, 1) void cluster_k(
    float* qbuf, const float* __restrict__ vbuf,
    const float* __restrict__ alpha_p, const float* __restrict__ beta_p)
{
  const int be = blockIdx.x;                 // b*4 + e
  const size_t base = (size_t)be * 24 * SP;
  float* qp = qbuf + base;
  const float* vp = vbuf + base;

  __shared__ double cnd[24][16];             // [c][f*4+m] pooled->normalized q centers
  __shared__ float  sbest[SP];
  __shared__ unsigned char ibest[SP];
  __shared__ float  clr[16][24];             // masked segment sums
  __shared__ float  vcr[16][24];             // pooled value centers (mean)
  __shared__ float  clf[16][25];             // final cluster vectors (padded)
  __shared__ float  dnf[16];

  const int tid  = threadIdx.x;
  const int wid  = tid >> 6;
  const int lane = tid & 63;

  // ---- phase 1: pooled q centers, one wave per (c,f) ----
  for (int p = wid; p < 96; p += 16) {
    const int c = p >> 2, f = p & 3;
    const int f1 = f >> 1, f2 = f & 1;
    const float* src = qp + (size_t)c * SP + f1 * 28 * ROW + f2 * 28;
    double s0=0.0, s1=0.0, s2=0.0, s3=0.0;
    for (int n = lane; n < 784; n += 64) {
      const int w = n / 28, h = n - w * 28;
      const double val = (double)src[w * ROW + h];
      const int mm = ((w >= 14) ? 2 : 0) + ((h >= 14) ? 1 : 0);
      s0 += (mm == 0) ? val : 0.0;
      s1 += (mm == 1) ? val : 0.0;
      s2 += (mm == 2) ? val : 0.0;
      s3 += (mm == 3) ? val : 0.0;
    }
    #pragma unroll
    for (int msk = 32; msk >= 1; msk >>= 1) {
      s0 += __shfl_xor(s0, msk); s1 += __shfl_xor(s1, msk);
      s2 += __shfl_xor(s2, msk); s3 += __shfl_xor(s3, msk);
    }
    if (lane == 0) {
      cnd[c][f*4+0] = s0 * (1.0/196.0);
      cnd[c][f*4+1] = s1 * (1.0/196.0);
      cnd[c][f*4+2] = s2 * (1.0/196.0);
      cnd[c][f*4+3] = s3 * (1.0/196.0);
    }
  }
  __syncthreads();
  if (tid < 16) {
    double s = 0.0;
    #pragma unroll
    for (int c = 0; c < 24; ++c) { double t = cnd[c][tid]; s += t * t; }
    const double inv = 1.0 / fmax(sqrt(s), 1e-12);
    #pragma unroll
    for (int c = 0; c < 24; ++c) cnd[c][tid] *= inv;
  }
  __syncthreads();

  const double alpha = (double)alpha_p[0];
  const double beta  = (double)beta_p[0];

  // ---- phase 2: channel-major z dots (fp64), argmax, sigmoid ----
  {
    const int s0 = tid, s1 = tid + 1024, s2 = tid + 2048, s3 = tid + 3072;
    const bool has4 = (tid < 64);
    const int fa = ((s0/56) >= 28 ? 2 : 0) + ((s0%56) >= 28 ? 1 : 0);
    const int fb = ((s1/56) >= 28 ? 2 : 0) + ((s1%56) >= 28 ? 1 : 0);
    const int fc = ((s2/56) >= 28 ? 2 : 0) + ((s2%56) >= 28 ? 1 : 0);
    const int fd = ((s3/56) >= 28 ? 2 : 0) + ((s3%56) >= 28 ? 1 : 0);
    double za0=0,za1=0,za2=0,za3=0, zb0=0,zb1=0,zb2=0,zb3=0;
    double zc0=0,zc1=0,zc2=0,zc3=0, zd0=0,zd1=0,zd2=0,zd3=0;
    double na=0, nb=0, ncn=0, nd=0;
    for (int c = 0; c < 24; ++c) {
      const float* qc = qp + (size_t)c * SP;
      const double qa = (double)qc[s0];
      const double qb = (double)qc[s1];
      const double qq = (double)qc[s2];
      const double qd = has4 ? (double)qc[s3] : 0.0;
      za0 += cnd[c][fa*4+0]*qa; za1 += cnd[c][fa*4+1]*qa;
      za2 += cnd[c][fa*4+2]*qa; za3 += cnd[c][fa*4+3]*qa;
      zb0 += cnd[c][fb*4+0]*qb; zb1 += cnd[c][fb*4+1]*qb;
      zb2 += cnd[c][fb*4+2]*qb; zb3 += cnd[c][fb*4+3]*qb;
      zc0 += cnd[c][fc*4+0]*qq; zc1 += cnd[c][fc*4+1]*qq;
      zc2 += cnd[c][fc*4+2]*qq; zc3 += cnd[c][fc*4+3]*qq;
      zd0 += cnd[c][fd*4+0]*qd; zd1 += cnd[c][fd*4+1]*qd;
      zd2 += cnd[c][fd*4+2]*qd; zd3 += cnd[c][fd*4+3]*qd;
      na += qa*qa; nb += qb*qb; ncn += qq*qq; nd += qd*qd;
    }
    auto finish = [&](double z0, double z1, double z2, double z3, double nn, int s) {
      const double inv = 1.0 / fmax(sqrt(nn), 1e-12);
      const double v0 = beta + alpha * (z0 * inv);
      const double v1 = beta + alpha * (z1 * inv);
      const double v2 = beta + alpha * (z2 * inv);
      const double v3 = beta + alpha * (z3 * inv);
      double zb_ = v0; int bi = 0;
      if (v1 > zb_) { zb_ = v1; bi = 1; }
      if (v2 > zb_) { zb_ = v2; bi = 2; }
      if (v3 > zb_) { zb_ = v3; bi = 3; }
      sbest[s] = (float)(1.0 / (1.0 + exp(-zb_)));
      ibest[s] = (unsigned char)bi;
    };
    finish(za0, za1, za2, za3, na,  s0);
    finish(zb0, zb1, zb2, zb3, nb,  s1);
    finish(zc0, zc1, zc2, zc3, ncn, s2);
    if (has4) finish(zd0, zd1, zd2, zd3, nd, s3);
  }
  __syncthreads();

  // ---- phase 3: masked segment sums + v pooling, one wave per (c,f); v read once ----
  for (int p = wid; p < 96; p += 16) {
    const int c = p >> 2, f = p & 3;
    const int f1 = f >> 1, f2 = f & 1;
    const int sgb = f1 * 28 * ROW + f2 * 28;
    const float* src = vp + (size_t)c * SP + sgb;
    float cl0=0,cl1=0,cl2=0,cl3=0, vc0=0,vc1=0,vc2=0,vc3=0, dn0=0,dn1=0,dn2=0,dn3=0;
    for (int n = lane; n < 784; n += 64) {
      const int w = n / 28, h = n - w * 28;
      const float v = src[w * ROW + h];
      const int sg = sgb + w * ROW + h;
      const float s = sbest[sg];
      const int  ib = ibest[sg];
      const float sv = s * v;
      cl0 += (ib==0)?sv:0.f; cl1 += (ib==1)?sv:0.f;
      cl2 += (ib==2)?sv:0.f; cl3 += (ib==3)?sv:0.f;
      const int mm = ((w >= 14) ? 2 : 0) + ((h >= 14) ? 1 : 0);
      vc0 += (mm==0)?v:0.f; vc1 += (mm==1)?v:0.f;
      vc2 += (mm==2)?v:0.f; vc3 += (mm==3)?v:0.f;
      dn0 += (ib==0)?s:0.f; dn1 += (ib==1)?s:0.f;
      dn2 += (ib==2)?s:0.f; dn3 += (ib==3)?s:0.f;
    }
    #pragma unroll
    for (int msk = 32; msk >= 1; msk >>= 1) {
      cl0 += __shfl_xor(cl0, msk); cl1 += __shfl_xor(cl1, msk);
      cl2 += __shfl_xor(cl2, msk); cl3 += __shfl_xor(cl3, msk);
      vc0 += __shfl_xor(vc0, msk); vc1 += __shfl_xor(vc1, msk);
      vc2 += __shfl_xor(vc2, msk); vc3 += __shfl_xor(vc3, msk);
      dn0 += __shfl_xor(dn0, msk); dn1 += __shfl_xor(dn1, msk);
      dn2 += __shfl_xor(dn2, msk); dn3 += __shfl_xor(dn3, msk);
    }
    if (lane == 0) {
      clr[f*4+0][c]=cl0; clr[f*4+1][c]=cl1; clr[f*4+2][c]=cl2; clr[f*4+3][c]=cl3;
      vcr[f*4+0][c]=vc0*(1.f/196.f); vcr[f*4+1][c]=vc1*(1.f/196.f);
      vcr[f*4+2][c]=vc2*(1.f/196.f); vcr[f*4+3][c]=vc3*(1.f/196.f);
      if (c == 0) {
        dnf[f*4+0]=dn0; dnf[f*4+1]=dn1; dnf[f*4+2]=dn2; dnf[f*4+3]=dn3;
      }
    }
  }
  __syncthreads();
  if (tid < 16 * 24) {
    const int g = tid / 24, c = tid - g * 24;
    clf[g][c] = (clr[g][c] + vcr[g][c]) / (dnf[g] + 1.0f);
  }
  __syncthreads();

  // ---- phase 4: patches = sbest * cluster[ibest], channel-major coalesced writes ----
  {
    const int s0 = tid, s1 = tid + 1024, s2 = tid + 2048, s3 = tid + 3072;
    const bool has4 = (tid < 64);
    const int fa = ((s0/56) >= 28 ? 2 : 0) + ((s0%56) >= 28 ? 1 : 0);
    const int fb = ((s1/56) >= 28 ? 2 : 0) + ((s1%56) >= 28 ? 1 : 0);
    const int fc = ((s2/56) >= 28 ? 2 : 0) + ((s2%56) >= 28 ? 1 : 0);
    const int fd = ((s3/56) >= 28 ? 2 : 0) + ((s3%56) >= 28 ? 1 : 0);
    const float b0 = sbest[s0]; const int g0 = fa*4 + ibest[s0];
    const float b1 = sbest[s1]; const int g1 = fb*4 + ibest[s1];
    const float b2 = sbest[s2]; const int g2 = fc*4 + ibest[s2];
    const float b3 = has4 ? sbest[s3] : 0.f;
    const int   g3 = has4 ? (fd*4 + ibest[s3]) : 0;
    for (int c = 0; c < 24; ++c) {
      float* qc = qp + (size_t)c * SP;
      qc[s0] = b0 * clf[g0][c];
      qc[s1] = b1 * clf[g1][c];
      qc[s2] = b2 * clf[g2][c];
      if (has4) qc[s3] = b3 * clf[g3][c];
    }
  }
}

// ---------------- Kernel 3: output 1x1 conv ----------------
__global__ __launch_bounds__(256) void out_conv(
    const float* __restrict__ pbuf, const float* __restrict__ Wo,
    const float* __restrict__ bo, float* __restrict__ out)
{
  const int st = blockIdx.x % 49;
  const int b  = blockIdx.x / 49;
  const float* pb = pbuf + (size_t)b * HD * SP + st * 64;

  __shared__ float xs[32][64];
  __shared__ float wl[32][132];

  const int tid = threadIdx.x;
  const int og = tid >> 4;
  const int sg = tid & 15;

  float acc[8][4];
  #pragma unroll
  for (int i = 0; i < 8; ++i) { acc[i][0]=0.f; acc[i][1]=0.f; acc[i][2]=0.f; acc[i][3]=0.f; }

  for (int kt = 0; kt < 3; ++kt) {
    __syncthreads();
    #pragma unroll
    for (int r = 0; r < 2; ++r) {
      int i = tid + r * 256;
      int cc = i >> 4, s4 = i & 15;
      float4 v = *reinterpret_cast<const float4*>(pb + (size_t)(kt*32 + cc) * SP + s4*4);
      *reinterpret_cast<float4*>(&xs[cc][s4*4]) = v;
    }
    #pragma unroll
    for (int r = 0; r < 4; ++r) {
      int i = tid + r * 256;
      int co = i >> 3, c4 = i & 7;
      float4 wv = *reinterpret_cast<const float4*>(Wo + (size_t)co * HD + kt*32 + c4*4);
      wl[c4*4+0][co] = wv.x; wl[c4*4+1][co] = wv.y;
      wl[c4*4+2][co] = wv.z; wl[c4*4+3][co] = wv.w;
    }
    __syncthreads();
    #pragma unroll
    for (int cc = 0; cc < 32; ++cc) {
      float xv[4];
      *reinterpret_cast<float4*>(xv) = *reinterpret_cast<const float4*>(&xs[cc][sg*4]);
      float wv[8];
      *reinterpret_cast<float4*>(wv + 0) = *reinterpret_cast<const float4*>(&wl[cc][og*8 + 0]);
      *reinterpret_cast<float4*>(wv + 4) = *reinterpret_cast<const float4*>(&wl[cc][og*8 + 4]);
      #pragma unroll
      for (int i = 0; i < 8; ++i)
        #pragma unroll
        for (int j = 0; j < 4; ++j)
          acc[i][j] = fmaf(wv[i], xv[j], acc[i][j]);
    }
  }
  #pragma unroll
  for (int i = 0; i < 8; ++i) {
    int co = og * 8 + i;
    float bias = bo[co];
    float4 v;
    v.x = acc[i][0] + bias; v.y = acc[i][1] + bias;
    v.z = acc[i][2] + bias; v.w = acc[i][3] + bias;
    *reinterpret_cast<float4*>(out + ((size_t)b*128 + co) * SP + st*64 + sg*4) = v;
  }
}

extern "C" void kernel_launch(void* const* d_in, const int* in_sizes, int n_in,
                              void* d_out, int out_size, void* d_ws, size_t ws_size,
                              hipStream_t stream) {
  const float* x  = (const float*)d_in[0];
  const float* Wc = (const float*)d_in[1];
  const float* bc = (const float*)d_in[2];
  const float* Wp = (const float*)d_in[3];
  const float* bp = (const float*)d_in[4];
  const float* sa = (const float*)d_in[5];
  const float* sb = (const float*)d_in[6];
  const float* Wo = (const float*)d_in[7];
  const float* bo = (const float*)d_in[8];
  float* out  = (float*)d_out;
  float* qbuf = (float*)d_ws;   // 77.1 MB; patches overwrite in-place
  float* vbuf = out;            // value scratch inside d_out; fully overwritten by out_conv

  qv_conv<<<dim3(64 * 49), dim3(256), 0, stream>>>(x, Wc, bc, Wp, bp, qbuf, vbuf);
  cluster_k<<<dim3(256), dim3(1024), 0, stream>>>(qbuf, vbuf, sa, sb);
  out_conv<<<dim3(64 * 49), dim3(256), 0, stream>>>(qbuf, Wo, bo, out);
}

// Round 4
// 309.454 us; speedup vs baseline: 2.2709x; 2.2709x over previous
//
#include <hip/hip_runtime.h>
#include <math.h>

#define CIN 128
#define HD  96
#define SP  3136   // 56*56
#define ROW 56

// ---------------- Kernel 1: q/value 1x1 conv (fused) ----------------
__global__ __launch_bounds__(256) void qv_conv(
    const float* __restrict__ x, const float* __restrict__ Wc,
    const float* __restrict__ bc, const float* __restrict__ Wp,
    const float* __restrict__ bp, float* __restrict__ qbuf,
    float* __restrict__ vbuf)
{
  const int st = blockIdx.x % 49;
  const int b  = blockIdx.x / 49;
  const float* xb = x + (size_t)b * CIN * SP + st * 64;

  __shared__ float xs[32][64];
  __shared__ float wl[32][196];

  const int tid = threadIdx.x;
  const int og = tid >> 4;
  const int sg = tid & 15;

  float acc[12][4];
  #pragma unroll
  for (int i = 0; i < 12; ++i) { acc[i][0]=0.f; acc[i][1]=0.f; acc[i][2]=0.f; acc[i][3]=0.f; }

  for (int kt = 0; kt < 4; ++kt) {
    __syncthreads();
    #pragma unroll
    for (int r = 0; r < 2; ++r) {
      int i = tid + r * 256;
      int cc = i >> 4, s4 = i & 15;
      float4 v = *reinterpret_cast<const float4*>(xb + (size_t)(kt*32 + cc) * SP + s4*4);
      *reinterpret_cast<float4*>(&xs[cc][s4*4]) = v;
    }
    #pragma unroll
    for (int r = 0; r < 6; ++r) {
      int i = tid + r * 256;
      int o  = i >> 3, c4 = i & 7;
      const float* wrow = (o < 96) ? (Wc + (size_t)o * CIN) : (Wp + (size_t)(o - 96) * CIN);
      float4 wv = *reinterpret_cast<const float4*>(wrow + kt*32 + c4*4);
      wl[c4*4+0][o] = wv.x; wl[c4*4+1][o] = wv.y;
      wl[c4*4+2][o] = wv.z; wl[c4*4+3][o] = wv.w;
    }
    __syncthreads();
    #pragma unroll
    for (int cc = 0; cc < 32; ++cc) {
      float xv[4];
      *reinterpret_cast<float4*>(xv) = *reinterpret_cast<const float4*>(&xs[cc][sg*4]);
      float wv[12];
      *reinterpret_cast<float4*>(wv + 0) = *reinterpret_cast<const float4*>(&wl[cc][og*12 + 0]);
      *reinterpret_cast<float4*>(wv + 4) = *reinterpret_cast<const float4*>(&wl[cc][og*12 + 4]);
      *reinterpret_cast<float4*>(wv + 8) = *reinterpret_cast<const float4*>(&wl[cc][og*12 + 8]);
      #pragma unroll
      for (int i = 0; i < 12; ++i)
        #pragma unroll
        for (int j = 0; j < 4; ++j)
          acc[i][j] = fmaf(wv[i], xv[j], acc[i][j]);
    }
  }
  #pragma unroll
  for (int i = 0; i < 12; ++i) {
    int o = og * 12 + i;
    float bias; float* dst;
    if (o < 96) { bias = bc[o];      dst = qbuf + ((size_t)b*96 + o      ) * SP + st*64; }
    else        { bias = bp[o - 96]; dst = vbuf + ((size_t)b*96 + (o - 96)) * SP + st*64; }
    float4 v;
    v.x = acc[i][0] + bias; v.y = acc[i][1] + bias;
    v.z = acc[i][2] + bias; v.w = acc[i][3] + bias;
    *reinterpret_cast<float4*>(dst + sg*4) = v;
  }
}

// ---------------- Kernel 2: clustering, one 512-thread block per (b,e,f1) ----------------
// Block owns a 24-channel 28x56 slab (both f2 folds). Per-channel slab offset == n
// (rows are full 56-wide) -> every global access is a contiguous full-line run.
__global__ __launch_bounds__(512, 4) void cluster_k(
    float* qbuf, const float* __restrict__ vbuf,
    const float* __restrict__ alpha_p, const float* __restrict__ beta_p)
{
  const int blk = blockIdx.x;              // (b*4+e)*2 + f1
  const int f1  = blk & 1;
  const int be  = blk >> 1;
  const size_t base = (size_t)be * 24 * SP + (size_t)(f1 * 28) * ROW;
  float* qp = qbuf + base;
  const float* vp = vbuf + base;

  __shared__ double cnd[24][8];     // normalized q centers [c][g], g = f2*4+m
  __shared__ float  sbest[1568];
  __shared__ unsigned char ibest[1568];
  __shared__ float  clr[8][24];
  __shared__ float  vcr[8][24];
  __shared__ float  dnf[8];
  __shared__ float  clf[8][25];

  const int tid  = threadIdx.x;
  const int wid  = tid >> 6;
  const int lane = tid & 63;

  // ---- phase 1: pooled q centers (wave per channel, 8 masked bins) ----
  for (int c = wid; c < 24; c += 8) {
    const float* src = qp + (size_t)c * SP;
    double b0=0,b1=0,b2=0,b3=0,b4=0,b5=0,b6=0,b7=0;
    for (int n = lane; n < 1568; n += 64) {
      const int w = n / 56, h = n - w * 56;
      const int hf = (h >= 28) ? (h - 28) : h;
      const int g  = ((h >= 28) ? 4 : 0) + ((w >= 14) ? 2 : 0) + ((hf >= 14) ? 1 : 0);
      const double val = (double)src[n];
      b0 += (g==0)?val:0.0; b1 += (g==1)?val:0.0;
      b2 += (g==2)?val:0.0; b3 += (g==3)?val:0.0;
      b4 += (g==4)?val:0.0; b5 += (g==5)?val:0.0;
      b6 += (g==6)?val:0.0; b7 += (g==7)?val:0.0;
    }
    #pragma unroll
    for (int m = 32; m >= 1; m >>= 1) {
      b0 += __shfl_xor(b0,m); b1 += __shfl_xor(b1,m);
      b2 += __shfl_xor(b2,m); b3 += __shfl_xor(b3,m);
      b4 += __shfl_xor(b4,m); b5 += __shfl_xor(b5,m);
      b6 += __shfl_xor(b6,m); b7 += __shfl_xor(b7,m);
    }
    if (lane == 0) {
      cnd[c][0]=b0*(1.0/196.0); cnd[c][1]=b1*(1.0/196.0);
      cnd[c][2]=b2*(1.0/196.0); cnd[c][3]=b3*(1.0/196.0);
      cnd[c][4]=b4*(1.0/196.0); cnd[c][5]=b5*(1.0/196.0);
      cnd[c][6]=b6*(1.0/196.0); cnd[c][7]=b7*(1.0/196.0);
    }
  }
  __syncthreads();
  if (tid < 8) {
    double s = 0.0;
    #pragma unroll
    for (int c = 0; c < 24; ++c) { double t = cnd[c][tid]; s += t * t; }
    const double inv = 1.0 / fmax(sqrt(s), 1e-12);
    #pragma unroll
    for (int c = 0; c < 24; ++c) cnd[c][tid] *= inv;
  }
  __syncthreads();

  const double alpha = (double)alpha_p[0];
  const double beta  = (double)beta_p[0];

  // ---- phase 2: fp64 z dots, strict-first argmax, one sigmoid ----
  for (int n0 = tid; n0 < 1568; n0 += 512) {
    const int h  = n0 % 56;
    const int gb = (h >= 28) ? 4 : 0;
    double z0=0,z1=0,z2=0,z3=0,nrm=0;
    for (int c = 0; c < 24; ++c) {
      const double qv = (double)qp[(size_t)c * SP + n0];
      z0 += cnd[c][gb+0]*qv; z1 += cnd[c][gb+1]*qv;
      z2 += cnd[c][gb+2]*qv; z3 += cnd[c][gb+3]*qv;
      nrm += qv*qv;
    }
    const double inv = 1.0 / fmax(sqrt(nrm), 1e-12);
    const double v0 = beta + alpha * (z0 * inv);
    const double v1 = beta + alpha * (z1 * inv);
    const double v2 = beta + alpha * (z2 * inv);
    const double v3 = beta + alpha * (z3 * inv);
    double zb = v0; int bi = 0;
    if (v1 > zb) { zb = v1; bi = 1; }
    if (v2 > zb) { zb = v2; bi = 2; }
    if (v3 > zb) { zb = v3; bi = 3; }
    sbest[n0] = (float)(1.0 / (1.0 + exp(-zb)));
    ibest[n0] = (unsigned char)bi;
  }
  __syncthreads();

  // ---- phase 3: masked segment sums + v pooling (v read once), wave per channel ----
  for (int c = wid; c < 24; c += 8) {
    const float* vsrc = vp + (size_t)c * SP;
    float cl0=0,cl1=0,cl2=0,cl3=0,cl4=0,cl5=0,cl6=0,cl7=0;
    float vc0=0,vc1=0,vc2=0,vc3=0,vc4=0,vc5=0,vc6=0,vc7=0;
    float dn0=0,dn1=0,dn2=0,dn3=0,dn4=0,dn5=0,dn6=0,dn7=0;
    for (int n = lane; n < 1568; n += 64) {
      const int w = n / 56, h = n - w * 56;
      const int hf = (h >= 28) ? (h - 28) : h;
      const int fb = (h >= 28) ? 4 : 0;
      const float v = vsrc[n];
      const float s = sbest[n];
      const int gi = fb + ibest[n];
      const int gm = fb + ((w >= 14) ? 2 : 0) + ((hf >= 14) ? 1 : 0);
      const float sv = s * v;
      cl0 += (gi==0)?sv:0.f; cl1 += (gi==1)?sv:0.f;
      cl2 += (gi==2)?sv:0.f; cl3 += (gi==3)?sv:0.f;
      cl4 += (gi==4)?sv:0.f; cl5 += (gi==5)?sv:0.f;
      cl6 += (gi==6)?sv:0.f; cl7 += (gi==7)?sv:0.f;
      vc0 += (gm==0)?v:0.f;  vc1 += (gm==1)?v:0.f;
      vc2 += (gm==2)?v:0.f;  vc3 += (gm==3)?v:0.f;
      vc4 += (gm==4)?v:0.f;  vc5 += (gm==5)?v:0.f;
      vc6 += (gm==6)?v:0.f;  vc7 += (gm==7)?v:0.f;
      dn0 += (gi==0)?s:0.f;  dn1 += (gi==1)?s:0.f;
      dn2 += (gi==2)?s:0.f;  dn3 += (gi==3)?s:0.f;
      dn4 += (gi==4)?s:0.f;  dn5 += (gi==5)?s:0.f;
      dn6 += (gi==6)?s:0.f;  dn7 += (gi==7)?s:0.f;
    }
    #pragma unroll
    for (int m = 32; m >= 1; m >>= 1) {
      cl0 += __shfl_xor(cl0,m); cl1 += __shfl_xor(cl1,m);
      cl2 += __shfl_xor(cl2,m); cl3 += __shfl_xor(cl3,m);
      cl4 += __shfl_xor(cl4,m); cl5 += __shfl_xor(cl5,m);
      cl6 += __shfl_xor(cl6,m); cl7 += __shfl_xor(cl7,m);
      vc0 += __shfl_xor(vc0,m); vc1 += __shfl_xor(vc1,m);
      vc2 += __shfl_xor(vc2,m); vc3 += __shfl_xor(vc3,m);
      vc4 += __shfl_xor(vc4,m); vc5 += __shfl_xor(vc5,m);
      vc6 += __shfl_xor(vc6,m); vc7 += __shfl_xor(vc7,m);
      dn0 += __shfl_xor(dn0,m); dn1 += __shfl_xor(dn1,m);
      dn2 += __shfl_xor(dn2,m); dn3 += __shfl_xor(dn3,m);
      dn4 += __shfl_xor(dn4,m); dn5 += __shfl_xor(dn5,m);
      dn6 += __shfl_xor(dn6,m); dn7 += __shfl_xor(dn7,m);
    }
    if (lane == 0) {
      clr[0][c]=cl0; clr[1][c]=cl1; clr[2][c]=cl2; clr[3][c]=cl3;
      clr[4][c]=cl4; clr[5][c]=cl5; clr[6][c]=cl6; clr[7][c]=cl7;
      vcr[0][c]=vc0*(1.f/196.f); vcr[1][c]=vc1*(1.f/196.f);
      vcr[2][c]=vc2*(1.f/196.f); vcr[3][c]=vc3*(1.f/196.f);
      vcr[4][c]=vc4*(1.f/196.f); vcr[5][c]=vc5*(1.f/196.f);
      vcr[6][c]=vc6*(1.f/196.f); vcr[7][c]=vc7*(1.f/196.f);
      if (c == 0) {
        dnf[0]=dn0; dnf[1]=dn1; dnf[2]=dn2; dnf[3]=dn3;
        dnf[4]=dn4; dnf[5]=dn5; dnf[6]=dn6; dnf[7]=dn7;
      }
    }
  }
  __syncthreads();
  if (tid < 192) {
    const int g = tid / 24, c = tid - g * 24;
    clf[g][c] = (clr[g][c] + vcr[g][c]) / (dnf[g] + 1.0f);
  }
  __syncthreads();

  // ---- phase 4: patches = sbest * cluster[ibest], contiguous per-channel writes ----
  {
    const int n0 = tid, n1 = tid + 512, n2 = tid + 1024, n3 = tid + 1536;
    const bool has4 = (n3 < 1568);
    const float s0 = sbest[n0], s1 = sbest[n1], s2 = sbest[n2];
    const float s3 = has4 ? sbest[n3] : 0.f;
    const int g0 = (((n0 % 56) >= 28) ? 4 : 0) + ibest[n0];
    const int g1 = (((n1 % 56) >= 28) ? 4 : 0) + ibest[n1];
    const int g2 = (((n2 % 56) >= 28) ? 4 : 0) + ibest[n2];
    const int g3 = has4 ? ((((n3 % 56) >= 28) ? 4 : 0) + ibest[n3]) : 0;
    for (int c = 0; c < 24; ++c) {
      float* qc = qp + (size_t)c * SP;
      qc[n0] = s0 * clf[g0][c];
      qc[n1] = s1 * clf[g1][c];
      qc[n2] = s2 * clf[g2][c];
      if (has4) qc[n3] = s3 * clf[g3][c];
    }
  }
}

// ---------------- Kernel 3: output 1x1 conv ----------------
__global__ __launch_bounds__(256) void out_conv(
    const float* __restrict__ pbuf, const float* __restrict__ Wo,
    const float* __restrict__ bo, float* __restrict__ out)
{
  const int st = blockIdx.x % 49;
  const int b  = blockIdx.x / 49;
  const float* pb = pbuf + (size_t)b * HD * SP + st * 64;

  __shared__ float xs[32][64];
  __shared__ float wl[32][132];

  const int tid = threadIdx.x;
  const int og = tid >> 4;
  const int sg = tid & 15;

  float acc[8][4];
  #pragma unroll
  for (int i = 0; i < 8; ++i) { acc[i][0]=0.f; acc[i][1]=0.f; acc[i][2]=0.f; acc[i][3]=0.f; }

  for (int kt = 0; kt < 3; ++kt) {
    __syncthreads();
    #pragma unroll
    for (int r = 0; r < 2; ++r) {
      int i = tid + r * 256;
      int cc = i >> 4, s4 = i & 15;
      float4 v = *reinterpret_cast<const float4*>(pb + (size_t)(kt*32 + cc) * SP + s4*4);
      *reinterpret_cast<float4*>(&xs[cc][s4*4]) = v;
    }
    #pragma unroll
    for (int r = 0; r < 4; ++r) {
      int i = tid + r * 256;
      int co = i >> 3, c4 = i & 7;
      float4 wv = *reinterpret_cast<const float4*>(Wo + (size_t)co * HD + kt*32 + c4*4);
      wl[c4*4+0][co] = wv.x; wl[c4*4+1][co] = wv.y;
      wl[c4*4+2][co] = wv.z; wl[c4*4+3][co] = wv.w;
    }
    __syncthreads();
    #pragma unroll
    for (int cc = 0; cc < 32; ++cc) {
      float xv[4];
      *reinterpret_cast<float4*>(xv) = *reinterpret_cast<const float4*>(&xs[cc][sg*4]);
      float wv[8];
      *reinterpret_cast<float4*>(wv + 0) = *reinterpret_cast<const float4*>(&wl[cc][og*8 + 0]);
      *reinterpret_cast<float4*>(wv + 4) = *reinterpret_cast<const float4*>(&wl[cc][og*8 + 4]);
      #pragma unroll
      for (int i = 0; i < 8; ++i)
        #pragma unroll
        for (int j = 0; j < 4; ++j)
          acc[i][j] = fmaf(wv[i], xv[j], acc[i][j]);
    }
  }
  #pragma unroll
  for (int i = 0; i < 8; ++i) {
    int co = og * 8 + i;
    float bias = bo[co];
    float4 v;
    v.x = acc[i][0] + bias; v.y = acc[i][1] + bias;
    v.z = acc[i][2] + bias; v.w = acc[i][3] + bias;
    *reinterpret_cast<float4*>(out + ((size_t)b*128 + co) * SP + st*64 + sg*4) = v;
  }
}

extern "C" void kernel_launch(void* const* d_in, const int* in_sizes, int n_in,
                              void* d_out, int out_size, void* d_ws, size_t ws_size,
                              hipStream_t stream) {
  const float* x  = (const float*)d_in[0];
  const float* Wc = (const float*)d_in[1];
  const float* bc = (const float*)d_in[2];
  const float* Wp = (const float*)d_in[3];
  const float* bp = (const float*)d_in[4];
  const float* sa = (const float*)d_in[5];
  const float* sb = (const float*)d_in[6];
  const float* Wo = (const float*)d_in[7];
  const float* bo = (const float*)d_in[8];
  float* out  = (float*)d_out;
  float* qbuf = (float*)d_ws;   // 77.1 MB; patches overwrite in-place
  float* vbuf = out;            // value scratch inside d_out; fully overwritten by out_conv

  qv_conv<<<dim3(64 * 49), dim3(256), 0, stream>>>(x, Wc, bc, Wp, bp, qbuf, vbuf);
  cluster_k<<<dim3(512), dim3(512), 0, stream>>>(qbuf, vbuf, sa, sb);
  out_conv<<<dim3(64 * 49), dim3(256), 0, stream>>>(qbuf, Wo, bo, out);
}

// Round 5
// 308.402 us; speedup vs baseline: 2.2786x; 1.0034x over previous
//
#include <hip/hip_runtime.h>
#include <math.h>

#define CIN 128
#define HD  96
#define SP  3136   // 56*56
#define ROW 56

// ---------------- Kernel 1: q/value 1x1 conv (fused), batch-paired ----------------
// Each block: 2 batch images x 192 outputs x 64 spatial. W tile staged once per kt,
// shared across both images -> 5 ds_read_b128 per 96 FMA.
__global__ __launch_bounds__(256) void qv_conv(
    const float* __restrict__ x, const float* __restrict__ Wc,
    const float* __restrict__ bc, const float* __restrict__ Wp,
    const float* __restrict__ bp, float* __restrict__ qbuf,
    float* __restrict__ vbuf)
{
  const int st = blockIdx.x % 49;
  const int bp_ = blockIdx.x / 49;        // batch pair
  const int b0 = bp_ * 2;
  const float* xb = x + (size_t)b0 * CIN * SP + st * 64;

  __shared__ float xs[2][32][64];   // 16 KB
  __shared__ float wl[32][196];     // 24.5 KB

  const int tid = threadIdx.x;
  const int og = tid >> 4;          // 0..15 -> o0 = og*12
  const int sg = tid & 15;          // 0..15 -> s0 = sg*4

  float acc[12][8];
  #pragma unroll
  for (int i = 0; i < 12; ++i)
    #pragma unroll
    for (int j = 0; j < 8; ++j) acc[i][j] = 0.f;

  for (int kt = 0; kt < 4; ++kt) {
    __syncthreads();
    // stage x tiles for both images: 1024 float4 tasks
    #pragma unroll
    for (int r = 0; r < 4; ++r) {
      int i = tid + r * 256;
      int bsel = i >> 9, cc = (i >> 4) & 31, s4 = i & 15;
      float4 v = *reinterpret_cast<const float4*>(
          xb + ((size_t)bsel * CIN + kt*32 + cc) * SP + s4*4);
      *reinterpret_cast<float4*>(&xs[bsel][cc][s4*4]) = v;
    }
    // stage W tile transposed: wl[cc][o]
    #pragma unroll
    for (int r = 0; r < 6; ++r) {
      int i = tid + r * 256;
      int o  = i >> 3, c4 = i & 7;
      const float* wrow = (o < 96) ? (Wc + (size_t)o * CIN) : (Wp + (size_t)(o - 96) * CIN);
      float4 wv = *reinterpret_cast<const float4*>(wrow + kt*32 + c4*4);
      wl[c4*4+0][o] = wv.x; wl[c4*4+1][o] = wv.y;
      wl[c4*4+2][o] = wv.z; wl[c4*4+3][o] = wv.w;
    }
    __syncthreads();
    #pragma unroll
    for (int cc = 0; cc < 32; ++cc) {
      float xa[4], xb2[4];
      *reinterpret_cast<float4*>(xa)  = *reinterpret_cast<const float4*>(&xs[0][cc][sg*4]);
      *reinterpret_cast<float4*>(xb2) = *reinterpret_cast<const float4*>(&xs[1][cc][sg*4]);
      float wv[12];
      *reinterpret_cast<float4*>(wv + 0) = *reinterpret_cast<const float4*>(&wl[cc][og*12 + 0]);
      *reinterpret_cast<float4*>(wv + 4) = *reinterpret_cast<const float4*>(&wl[cc][og*12 + 4]);
      *reinterpret_cast<float4*>(wv + 8) = *reinterpret_cast<const float4*>(&wl[cc][og*12 + 8]);
      #pragma unroll
      for (int i = 0; i < 12; ++i) {
        #pragma unroll
        for (int j = 0; j < 4; ++j) {
          acc[i][j]   = fmaf(wv[i], xa[j],  acc[i][j]);
          acc[i][j+4] = fmaf(wv[i], xb2[j], acc[i][j+4]);
        }
      }
    }
  }
  #pragma unroll
  for (int i = 0; i < 12; ++i) {
    const int o = og * 12 + i;
    float bias; size_t off0;
    if (o < 96) { bias = bc[o];      off0 = ((size_t)b0*96 + o       ) * SP + st*64; }
    else        { bias = bp[o - 96]; off0 = ((size_t)b0*96 + (o - 96)) * SP + st*64; }
    float* dst = (o < 96) ? qbuf : vbuf;
    float4 v0, v1;
    v0.x = acc[i][0] + bias; v0.y = acc[i][1] + bias;
    v0.z = acc[i][2] + bias; v0.w = acc[i][3] + bias;
    v1.x = acc[i][4] + bias; v1.y = acc[i][5] + bias;
    v1.z = acc[i][6] + bias; v1.w = acc[i][7] + bias;
    *reinterpret_cast<float4*>(dst + off0 + sg*4) = v0;
    *reinterpret_cast<float4*>(dst + off0 + (size_t)96 * SP + sg*4) = v1;
  }
}

// ---------------- Kernel 2: clustering, one 512-thread block per (b,e,f1) ----------------
__global__ __launch_bounds__(512, 4) void cluster_k(
    float* qbuf, const float* __restrict__ vbuf,
    const float* __restrict__ alpha_p, const float* __restrict__ beta_p)
{
  const int blk = blockIdx.x;              // (b*4+e)*2 + f1
  const int f1  = blk & 1;
  const int be  = blk >> 1;
  const size_t base = (size_t)be * 24 * SP + (size_t)(f1 * 28) * ROW;
  float* qp = qbuf + base;
  const float* vp = vbuf + base;

  __shared__ double cnd[24][8];
  __shared__ float  sbest[1568];
  __shared__ unsigned char ibest[1568];
  __shared__ float  clr[8][24];
  __shared__ float  vcr[8][24];
  __shared__ float  dnf[8];
  __shared__ float  clf[8][25];

  const int tid  = threadIdx.x;
  const int wid  = tid >> 6;
  const int lane = tid & 63;

  for (int c = wid; c < 24; c += 8) {
    const float* src = qp + (size_t)c * SP;
    double b0=0,b1=0,b2=0,b3=0,b4=0,b5=0,b6=0,b7=0;
    for (int n = lane; n < 1568; n += 64) {
      const int w = n / 56, h = n - w * 56;
      const int hf = (h >= 28) ? (h - 28) : h;
      const int g  = ((h >= 28) ? 4 : 0) + ((w >= 14) ? 2 : 0) + ((hf >= 14) ? 1 : 0);
      const double val = (double)src[n];
      b0 += (g==0)?val:0.0; b1 += (g==1)?val:0.0;
      b2 += (g==2)?val:0.0; b3 += (g==3)?val:0.0;
      b4 += (g==4)?val:0.0; b5 += (g==5)?val:0.0;
      b6 += (g==6)?val:0.0; b7 += (g==7)?val:0.0;
    }
    #pragma unroll
    for (int m = 32; m >= 1; m >>= 1) {
      b0 += __shfl_xor(b0,m); b1 += __shfl_xor(b1,m);
      b2 += __shfl_xor(b2,m); b3 += __shfl_xor(b3,m);
      b4 += __shfl_xor(b4,m); b5 += __shfl_xor(b5,m);
      b6 += __shfl_xor(b6,m); b7 += __shfl_xor(b7,m);
    }
    if (lane == 0) {
      cnd[c][0]=b0*(1.0/196.0); cnd[c][1]=b1*(1.0/196.0);
      cnd[c][2]=b2*(1.0/196.0); cnd[c][3]=b3*(1.0/196.0);
      cnd[c][4]=b4*(1.0/196.0); cnd[c][5]=b5*(1.0/196.0);
      cnd[c][6]=b6*(1.0/196.0); cnd[c][7]=b7*(1.0/196.0);
    }
  }
  __syncthreads();
  if (tid < 8) {
    double s = 0.0;
    #pragma unroll
    for (int c = 0; c < 24; ++c) { double t = cnd[c][tid]; s += t * t; }
    const double inv = 1.0 / fmax(sqrt(s), 1e-12);
    #pragma unroll
    for (int c = 0; c < 24; ++c) cnd[c][tid] *= inv;
  }
  __syncthreads();

  const double alpha = (double)alpha_p[0];
  const double beta  = (double)beta_p[0];

  for (int n0 = tid; n0 < 1568; n0 += 512) {
    const int h  = n0 % 56;
    const int gb = (h >= 28) ? 4 : 0;
    double z0=0,z1=0,z2=0,z3=0,nrm=0;
    for (int c = 0; c < 24; ++c) {
      const double qv = (double)qp[(size_t)c * SP + n0];
      z0 += cnd[c][gb+0]*qv; z1 += cnd[c][gb+1]*qv;
      z2 += cnd[c][gb+2]*qv; z3 += cnd[c][gb+3]*qv;
      nrm += qv*qv;
    }
    const double inv = 1.0 / fmax(sqrt(nrm), 1e-12);
    const double v0 = beta + alpha * (z0 * inv);
    const double v1 = beta + alpha * (z1 * inv);
    const double v2 = beta + alpha * (z2 * inv);
    const double v3 = beta + alpha * (z3 * inv);
    double zb = v0; int bi = 0;
    if (v1 > zb) { zb = v1; bi = 1; }
    if (v2 > zb) { zb = v2; bi = 2; }
    if (v3 > zb) { zb = v3; bi = 3; }
    sbest[n0] = (float)(1.0 / (1.0 + exp(-zb)));
    ibest[n0] = (unsigned char)bi;
  }
  __syncthreads();

  for (int c = wid; c < 24; c += 8) {
    const float* vsrc = vp + (size_t)c * SP;
    float cl0=0,cl1=0,cl2=0,cl3=0,cl4=0,cl5=0,cl6=0,cl7=0;
    float vc0=0,vc1=0,vc2=0,vc3=0,vc4=0,vc5=0,vc6=0,vc7=0;
    float dn0=0,dn1=0,dn2=0,dn3=0,dn4=0,dn5=0,dn6=0,dn7=0;
    for (int n = lane; n < 1568; n += 64) {
      const int w = n / 56, h = n - w * 56;
      const int hf = (h >= 28) ? (h - 28) : h;
      const int fb = (h >= 28) ? 4 : 0;
      const float v = vsrc[n];
      const float s = sbest[n];
      const int gi = fb + ibest[n];
      const int gm = fb + ((w >= 14) ? 2 : 0) + ((hf >= 14) ? 1 : 0);
      const float sv = s * v;
      cl0 += (gi==0)?sv:0.f; cl1 += (gi==1)?sv:0.f;
      cl2 += (gi==2)?sv:0.f; cl3 += (gi==3)?sv:0.f;
      cl4 += (gi==4)?sv:0.f; cl5 += (gi==5)?sv:0.f;
      cl6 += (gi==6)?sv:0.f; cl7 += (gi==7)?sv:0.f;
      vc0 += (gm==0)?v:0.f;  vc1 += (gm==1)?v:0.f;
      vc2 += (gm==2)?v:0.f;  vc3 += (gm==3)?v:0.f;
      vc4 += (gm==4)?v:0.f;  vc5 += (gm==5)?v:0.f;
      vc6 += (gm==6)?v:0.f;  vc7 += (gm==7)?v:0.f;
      dn0 += (gi==0)?s:0.f;  dn1 += (gi==1)?s:0.f;
      dn2 += (gi==2)?s:0.f;  dn3 += (gi==3)?s:0.f;
      dn4 += (gi==4)?s:0.f;  dn5 += (gi==5)?s:0.f;
      dn6 += (gi==6)?s:0.f;  dn7 += (gi==7)?s:0.f;
    }
    #pragma unroll
    for (int m = 32; m >= 1; m >>= 1) {
      cl0 += __shfl_xor(cl0,m); cl1 += __shfl_xor(cl1,m);
      cl2 += __shfl_xor(cl2,m); cl3 += __shfl_xor(cl3,m);
      cl4 += __shfl_xor(cl4,m); cl5 += __shfl_xor(cl5,m);
      cl6 += __shfl_xor(cl6,m); cl7 += __shfl_xor(cl7,m);
      vc0 += __shfl_xor(vc0,m); vc1 += __shfl_xor(vc1,m);
      vc2 += __shfl_xor(vc2,m); vc3 += __shfl_xor(vc3,m);
      vc4 += __shfl_xor(vc4,m); vc5 += __shfl_xor(vc5,m);
      vc6 += __shfl_xor(vc6,m); vc7 += __shfl_xor(vc7,m);
      dn0 += __shfl_xor(dn0,m); dn1 += __shfl_xor(dn1,m);
      dn2 += __shfl_xor(dn2,m); dn3 += __shfl_xor(dn3,m);
      dn4 += __shfl_xor(dn4,m); dn5 += __shfl_xor(dn5,m);
      dn6 += __shfl_xor(dn6,m); dn7 += __shfl_xor(dn7,m);
    }
    if (lane == 0) {
      clr[0][c]=cl0; clr[1][c]=cl1; clr[2][c]=cl2; clr[3][c]=cl3;
      clr[4][c]=cl4; clr[5][c]=cl5; clr[6][c]=cl6; clr[7][c]=cl7;
      vcr[0][c]=vc0*(1.f/196.f); vcr[1][c]=vc1*(1.f/196.f);
      vcr[2][c]=vc2*(1.f/196.f); vcr[3][c]=vc3*(1.f/196.f);
      vcr[4][c]=vc4*(1.f/196.f); vcr[5][c]=vc5*(1.f/196.f);
      vcr[6][c]=vc6*(1.f/196.f); vcr[7][c]=vc7*(1.f/196.f);
      if (c == 0) {
        dnf[0]=dn0; dnf[1]=dn1; dnf[2]=dn2; dnf[3]=dn3;
        dnf[4]=dn4; dnf[5]=dn5; dnf[6]=dn6; dnf[7]=dn7;
      }
    }
  }
  __syncthreads();
  if (tid < 192) {
    const int g = tid / 24, c = tid - g * 24;
    clf[g][c] = (clr[g][c] + vcr[g][c]) / (dnf[g] + 1.0f);
  }
  __syncthreads();

  {
    const int n0 = tid, n1 = tid + 512, n2 = tid + 1024, n3 = tid + 1536;
    const bool has4 = (n3 < 1568);
    const float s0 = sbest[n0], s1 = sbest[n1], s2 = sbest[n2];
    const float s3 = has4 ? sbest[n3] : 0.f;
    const int g0 = (((n0 % 56) >= 28) ? 4 : 0) + ibest[n0];
    const int g1 = (((n1 % 56) >= 28) ? 4 : 0) + ibest[n1];
    const int g2 = (((n2 % 56) >= 28) ? 4 : 0) + ibest[n2];
    const int g3 = has4 ? ((((n3 % 56) >= 28) ? 4 : 0) + ibest[n3]) : 0;
    for (int c = 0; c < 24; ++c) {
      float* qc = qp + (size_t)c * SP;
      qc[n0] = s0 * clf[g0][c];
      qc[n1] = s1 * clf[g1][c];
      qc[n2] = s2 * clf[g2][c];
      if (has4) qc[n3] = s3 * clf[g3][c];
    }
  }
}

// ---------------- Kernel 3: output 1x1 conv, batch-paired ----------------
__global__ __launch_bounds__(256) void out_conv(
    const float* __restrict__ pbuf, const float* __restrict__ Wo,
    const float* __restrict__ bo, float* __restrict__ out)
{
  const int st = blockIdx.x % 49;
  const int bp_ = blockIdx.x / 49;
  const int b0 = bp_ * 2;
  const float* pb = pbuf + (size_t)b0 * HD * SP + st * 64;

  __shared__ float xs[2][32][64];   // 16 KB
  __shared__ float wl[32][132];     // 16.9 KB

  const int tid = threadIdx.x;
  const int og = tid >> 4;          // co0 = og*8
  const int sg = tid & 15;

  float acc[8][8];
  #pragma unroll
  for (int i = 0; i < 8; ++i)
    #pragma unroll
    for (int j = 0; j < 8; ++j) acc[i][j] = 0.f;

  for (int kt = 0; kt < 3; ++kt) {
    __syncthreads();
    #pragma unroll
    for (int r = 0; r < 4; ++r) {
      int i = tid + r * 256;
      int bsel = i >> 9, cc = (i >> 4) & 31, s4 = i & 15;
      float4 v = *reinterpret_cast<const float4*>(
          pb + ((size_t)bsel * HD + kt*32 + cc) * SP + s4*4);
      *reinterpret_cast<float4*>(&xs[bsel][cc][s4*4]) = v;
    }
    #pragma unroll
    for (int r = 0; r < 4; ++r) {
      int i = tid + r * 256;
      int co = i >> 3, c4 = i & 7;
      float4 wv = *reinterpret_cast<const float4*>(Wo + (size_t)co * HD + kt*32 + c4*4);
      wl[c4*4+0][co] = wv.x; wl[c4*4+1][co] = wv.y;
      wl[c4*4+2][co] = wv.z; wl[c4*4+3][co] = wv.w;
    }
    __syncthreads();
    #pragma unroll
    for (int cc = 0; cc < 32; ++cc) {
      float xa[4], xb2[4];
      *reinterpret_cast<float4*>(xa)  = *reinterpret_cast<const float4*>(&xs[0][cc][sg*4]);
      *reinterpret_cast<float4*>(xb2) = *reinterpret_cast<const float4*>(&xs[1][cc][sg*4]);
      float wv[8];
      *reinterpret_cast<float4*>(wv + 0) = *reinterpret_cast<const float4*>(&wl[cc][og*8 + 0]);
      *reinterpret_cast<float4*>(wv + 4) = *reinterpret_cast<const float4*>(&wl[cc][og*8 + 4]);
      #pragma unroll
      for (int i = 0; i < 8; ++i) {
        #pragma unroll
        for (int j = 0; j < 4; ++j) {
          acc[i][j]   = fmaf(wv[i], xa[j],  acc[i][j]);
          acc[i][j+4] = fmaf(wv[i], xb2[j], acc[i][j+4]);
        }
      }
    }
  }
  #pragma unroll
  for (int i = 0; i < 8; ++i) {
    const int co = og * 8 + i;
    const float bias = bo[co];
    float4 v0, v1;
    v0.x = acc[i][0] + bias; v0.y = acc[i][1] + bias;
    v0.z = acc[i][2] + bias; v0.w = acc[i][3] + bias;
    v1.x = acc[i][4] + bias; v1.y = acc[i][5] + bias;
    v1.z = acc[i][6] + bias; v1.w = acc[i][7] + bias;
    const size_t off0 = ((size_t)b0*128 + co) * SP + st*64 + sg*4;
    *reinterpret_cast<float4*>(out + off0) = v0;
    *reinterpret_cast<float4*>(out + off0 + (size_t)128 * SP) = v1;
  }
}

extern "C" void kernel_launch(void* const* d_in, const int* in_sizes, int n_in,
                              void* d_out, int out_size, void* d_ws, size_t ws_size,
                              hipStream_t stream) {
  const float* x  = (const float*)d_in[0];
  const float* Wc = (const float*)d_in[1];
  const float* bc = (const float*)d_in[2];
  const float* Wp = (const float*)d_in[3];
  const float* bp = (const float*)d_in[4];
  const float* sa = (const float*)d_in[5];
  const float* sb = (const float*)d_in[6];
  const float* Wo = (const float*)d_in[7];
  const float* bo = (const float*)d_in[8];
  float* out  = (float*)d_out;
  float* qbuf = (float*)d_ws;   // 77.1 MB; patches overwrite in-place
  float* vbuf = out;            // value scratch inside d_out; fully overwritten by out_conv

  qv_conv<<<dim3(32 * 49), dim3(256), 0, stream>>>(x, Wc, bc, Wp, bp, qbuf, vbuf);
  cluster_k<<<dim3(512), dim3(512), 0, stream>>>(qbuf, vbuf, sa, sb);
  out_conv<<<dim3(32 * 49), dim3(256), 0, stream>>>(qbuf, Wo, bo, out);
}

// Round 7
// 265.843 us; speedup vs baseline: 2.6434x; 1.1601x over previous
//
#include <hip/hip_runtime.h>
#include <math.h>

#define CIN 128
#define HD  96
#define SP  3136   // 56*56
#define ROW 56
#define SLAB 1568  // 28*56

// ---------------- Kernel 1: q/value 1x1 conv (fused) — R4 version ----------------
__global__ __launch_bounds__(256) void qv_conv(
    const float* __restrict__ x, const float* __restrict__ Wc,
    const float* __restrict__ bc, const float* __restrict__ Wp,
    const float* __restrict__ bp, float* __restrict__ qbuf,
    float* __restrict__ vbuf)
{
  const int st = blockIdx.x % 49;
  const int b  = blockIdx.x / 49;
  const float* xb = x + (size_t)b * CIN * SP + st * 64;

  __shared__ float xs[32][64];
  __shared__ float wl[32][196];

  const int tid = threadIdx.x;
  const int og = tid >> 4;
  const int sg = tid & 15;

  float acc[12][4];
  #pragma unroll
  for (int i = 0; i < 12; ++i) { acc[i][0]=0.f; acc[i][1]=0.f; acc[i][2]=0.f; acc[i][3]=0.f; }

  for (int kt = 0; kt < 4; ++kt) {
    __syncthreads();
    #pragma unroll
    for (int r = 0; r < 2; ++r) {
      int i = tid + r * 256;
      int cc = i >> 4, s4 = i & 15;
      float4 v = *reinterpret_cast<const float4*>(xb + (size_t)(kt*32 + cc) * SP + s4*4);
      *reinterpret_cast<float4*>(&xs[cc][s4*4]) = v;
    }
    #pragma unroll
    for (int r = 0; r < 6; ++r) {
      int i = tid + r * 256;
      int o  = i >> 3, c4 = i & 7;
      const float* wrow = (o < 96) ? (Wc + (size_t)o * CIN) : (Wp + (size_t)(o - 96) * CIN);
      float4 wv = *reinterpret_cast<const float4*>(wrow + kt*32 + c4*4);
      wl[c4*4+0][o] = wv.x; wl[c4*4+1][o] = wv.y;
      wl[c4*4+2][o] = wv.z; wl[c4*4+3][o] = wv.w;
    }
    __syncthreads();
    #pragma unroll
    for (int cc = 0; cc < 32; ++cc) {
      float xv[4];
      *reinterpret_cast<float4*>(xv) = *reinterpret_cast<const float4*>(&xs[cc][sg*4]);
      float wv[12];
      *reinterpret_cast<float4*>(wv + 0) = *reinterpret_cast<const float4*>(&wl[cc][og*12 + 0]);
      *reinterpret_cast<float4*>(wv + 4) = *reinterpret_cast<const float4*>(&wl[cc][og*12 + 4]);
      *reinterpret_cast<float4*>(wv + 8) = *reinterpret_cast<const float4*>(&wl[cc][og*12 + 8]);
      #pragma unroll
      for (int i = 0; i < 12; ++i)
        #pragma unroll
        for (int j = 0; j < 4; ++j)
          acc[i][j] = fmaf(wv[i], xv[j], acc[i][j]);
    }
  }
  #pragma unroll
  for (int i = 0; i < 12; ++i) {
    int o = og * 12 + i;
    float bias; float* dst;
    if (o < 96) { bias = bc[o];      dst = qbuf + ((size_t)b*96 + o      ) * SP + st*64; }
    else        { bias = bp[o - 96]; dst = vbuf + ((size_t)b*96 + (o - 96)) * SP + st*64; }
    float4 v;
    v.x = acc[i][0] + bias; v.y = acc[i][1] + bias;
    v.z = acc[i][2] + bias; v.w = acc[i][3] + bias;
    *reinterpret_cast<float4*>(dst + sg*4) = v;
  }
}

// ---------------- Kernel 2: clustering per (b,e,f1); exports s/g/clf into dead q ----------------
__global__ __launch_bounds__(512, 4) void cluster_k(
    float* qbuf, const float* __restrict__ vbuf,
    const float* __restrict__ alpha_p, const float* __restrict__ beta_p)
{
  const int blk = blockIdx.x;              // (b*4+e)*2 + f1
  const int f1  = blk & 1;
  const int be  = blk >> 1;
  const size_t base = (size_t)be * 24 * SP + (size_t)(f1 * 28) * ROW;
  float* qp = qbuf + base;                 // slab view: qp + c*SP + n, n in [0,1568)
  const float* vp = vbuf + base;

  __shared__ double cnd[24][8];
  __shared__ float  sbest[SLAB];
  __shared__ unsigned char ibest[SLAB];    // stores g = f2*4 + argmax (0..7)
  __shared__ float  clr[8][24];
  __shared__ float  vcr[8][24];
  __shared__ float  dnf[8];

  const int tid  = threadIdx.x;
  const int wid  = tid >> 6;
  const int lane = tid & 63;

  // phase 1: pooled q centers
  for (int c = wid; c < 24; c += 8) {
    const float* src = qp + (size_t)c * SP;
    double b0=0,b1=0,b2=0,b3=0,b4=0,b5=0,b6=0,b7=0;
    for (int n = lane; n < SLAB; n += 64) {
      const int w = n / 56, h = n - w * 56;
      const int hf = (h >= 28) ? (h - 28) : h;
      const int g  = ((h >= 28) ? 4 : 0) + ((w >= 14) ? 2 : 0) + ((hf >= 14) ? 1 : 0);
      const double val = (double)src[n];
      b0 += (g==0)?val:0.0; b1 += (g==1)?val:0.0;
      b2 += (g==2)?val:0.0; b3 += (g==3)?val:0.0;
      b4 += (g==4)?val:0.0; b5 += (g==5)?val:0.0;
      b6 += (g==6)?val:0.0; b7 += (g==7)?val:0.0;
    }
    #pragma unroll
    for (int m = 32; m >= 1; m >>= 1) {
      b0 += __shfl_xor(b0,m); b1 += __shfl_xor(b1,m);
      b2 += __shfl_xor(b2,m); b3 += __shfl_xor(b3,m);
      b4 += __shfl_xor(b4,m); b5 += __shfl_xor(b5,m);
      b6 += __shfl_xor(b6,m); b7 += __shfl_xor(b7,m);
    }
    if (lane == 0) {
      cnd[c][0]=b0*(1.0/196.0); cnd[c][1]=b1*(1.0/196.0);
      cnd[c][2]=b2*(1.0/196.0); cnd[c][3]=b3*(1.0/196.0);
      cnd[c][4]=b4*(1.0/196.0); cnd[c][5]=b5*(1.0/196.0);
      cnd[c][6]=b6*(1.0/196.0); cnd[c][7]=b7*(1.0/196.0);
    }
  }
  __syncthreads();
  if (tid < 8) {
    double s = 0.0;
    #pragma unroll
    for (int c = 0; c < 24; ++c) { double t = cnd[c][tid]; s += t * t; }
    const double inv = 1.0 / fmax(sqrt(s), 1e-12);
    #pragma unroll
    for (int c = 0; c < 24; ++c) cnd[c][tid] *= inv;
  }
  __syncthreads();

  const double alpha = (double)alpha_p[0];
  const double beta  = (double)beta_p[0];

  // phase 2: fp64 z dots, strict-first argmax, one sigmoid
  for (int n0 = tid; n0 < SLAB; n0 += 512) {
    const int h  = n0 % 56;
    const int gb = (h >= 28) ? 4 : 0;
    double z0=0,z1=0,z2=0,z3=0,nrm=0;
    for (int c = 0; c < 24; ++c) {
      const double qv = (double)qp[(size_t)c * SP + n0];
      z0 += cnd[c][gb+0]*qv; z1 += cnd[c][gb+1]*qv;
      z2 += cnd[c][gb+2]*qv; z3 += cnd[c][gb+3]*qv;
      nrm += qv*qv;
    }
    const double inv = 1.0 / fmax(sqrt(nrm), 1e-12);
    const double v0 = beta + alpha * (z0 * inv);
    const double v1 = beta + alpha * (z1 * inv);
    const double v2 = beta + alpha * (z2 * inv);
    const double v3 = beta + alpha * (z3 * inv);
    double zb = v0; int bi = 0;
    if (v1 > zb) { zb = v1; bi = 1; }
    if (v2 > zb) { zb = v2; bi = 2; }
    if (v3 > zb) { zb = v3; bi = 3; }
    sbest[n0] = (float)(1.0 / (1.0 + exp(-zb)));
    ibest[n0] = (unsigned char)(gb + bi);
  }
  __syncthreads();

  // phase 3: masked segment sums + v pooling (v read once)
  for (int c = wid; c < 24; c += 8) {
    const float* vsrc = vp + (size_t)c * SP;
    float cl0=0,cl1=0,cl2=0,cl3=0,cl4=0,cl5=0,cl6=0,cl7=0;
    float vc0=0,vc1=0,vc2=0,vc3=0,vc4=0,vc5=0,vc6=0,vc7=0;
    float dn0=0,dn1=0,dn2=0,dn3=0,dn4=0,dn5=0,dn6=0,dn7=0;
    for (int n = lane; n < SLAB; n += 64) {
      const int w = n / 56, h = n - w * 56;
      const int hf = (h >= 28) ? (h - 28) : h;
      const int fb = (h >= 28) ? 4 : 0;
      const float v = vsrc[n];
      const float s = sbest[n];
      const int gi = ibest[n];                     // already f2*4+m
      const int gm = fb + ((w >= 14) ? 2 : 0) + ((hf >= 14) ? 1 : 0);
      const float sv = s * v;
      cl0 += (gi==0)?sv:0.f; cl1 += (gi==1)?sv:0.f;
      cl2 += (gi==2)?sv:0.f; cl3 += (gi==3)?sv:0.f;
      cl4 += (gi==4)?sv:0.f; cl5 += (gi==5)?sv:0.f;
      cl6 += (gi==6)?sv:0.f; cl7 += (gi==7)?sv:0.f;
      vc0 += (gm==0)?v:0.f;  vc1 += (gm==1)?v:0.f;
      vc2 += (gm==2)?v:0.f;  vc3 += (gm==3)?v:0.f;
      vc4 += (gm==4)?v:0.f;  vc5 += (gm==5)?v:0.f;
      vc6 += (gm==6)?v:0.f;  vc7 += (gm==7)?v:0.f;
      dn0 += (gi==0)?s:0.f;  dn1 += (gi==1)?s:0.f;
      dn2 += (gi==2)?s:0.f;  dn3 += (gi==3)?s:0.f;
      dn4 += (gi==4)?s:0.f;  dn5 += (gi==5)?s:0.f;
      dn6 += (gi==6)?s:0.f;  dn7 += (gi==7)?s:0.f;
    }
    #pragma unroll
    for (int m = 32; m >= 1; m >>= 1) {
      cl0 += __shfl_xor(cl0,m); cl1 += __shfl_xor(cl1,m);
      cl2 += __shfl_xor(cl2,m); cl3 += __shfl_xor(cl3,m);
      cl4 += __shfl_xor(cl4,m); cl5 += __shfl_xor(cl5,m);
      cl6 += __shfl_xor(cl6,m); cl7 += __shfl_xor(cl7,m);
      vc0 += __shfl_xor(vc0,m); vc1 += __shfl_xor(vc1,m);
      vc2 += __shfl_xor(vc2,m); vc3 += __shfl_xor(vc3,m);
      vc4 += __shfl_xor(vc4,m); vc5 += __shfl_xor(vc5,m);
      vc6 += __shfl_xor(vc6,m); vc7 += __shfl_xor(vc7,m);
      dn0 += __shfl_xor(dn0,m); dn1 += __shfl_xor(dn1,m);
      dn2 += __shfl_xor(dn2,m); dn3 += __shfl_xor(dn3,m);
      dn4 += __shfl_xor(dn4,m); dn5 += __shfl_xor(dn5,m);
      dn6 += __shfl_xor(dn6,m); dn7 += __shfl_xor(dn7,m);
    }
    if (lane == 0) {
      clr[0][c]=cl0; clr[1][c]=cl1; clr[2][c]=cl2; clr[3][c]=cl3;
      clr[4][c]=cl4; clr[5][c]=cl5; clr[6][c]=cl6; clr[7][c]=cl7;
      vcr[0][c]=vc0*(1.f/196.f); vcr[1][c]=vc1*(1.f/196.f);
      vcr[2][c]=vc2*(1.f/196.f); vcr[3][c]=vc3*(1.f/196.f);
      vcr[4][c]=vc4*(1.f/196.f); vcr[5][c]=vc5*(1.f/196.f);
      vcr[6][c]=vc6*(1.f/196.f); vcr[7][c]=vc7*(1.f/196.f);
      if (c == 0) {
        dnf[0]=dn0; dnf[1]=dn1; dnf[2]=dn2; dnf[3]=dn3;
        dnf[4]=dn4; dnf[5]=dn5; dnf[6]=dn6; dnf[7]=dn7;
      }
    }
  }
  __syncthreads();

  // phase 4: export clf (ch2), s (ch0), g (ch1) into this slab's dead q region
  if (tid < 192) {
    const int g = tid / 24, c = tid - g * 24;
    qp[2 * (size_t)SP + tid] = (clr[g][c] + vcr[g][c]) / (dnf[g] + 1.0f);
  }
  for (int i = tid; i < SLAB; i += 512) {
    qp[i] = sbest[i];
    reinterpret_cast<unsigned int*>(qp + SP)[i] = (unsigned int)ibest[i];
  }
}

// ---------------- Kernel 2b: proj[e*8+g][co] = Wo_e[co] . clf_e[g]  per (b,f1,e) ----------------
__global__ __launch_bounds__(256) void proj_k(
    float* qbuf, const float* __restrict__ Wo)
{
  const int bid = blockIdx.x;           // ((b*2+f1)*4 + e)
  const int e   = bid & 3;
  const int f1  = (bid >> 2) & 1;
  const int b   = bid >> 3;
  const float* clfg = qbuf + ((size_t)(b*4 + e) * 24 + 2) * SP + (size_t)(f1*28) * ROW;
  float* projb = qbuf + ((size_t)b * 96 + 3 + f1*3) * SP;   // head-0 channels 3..8

  __shared__ float clfs[8][24];
  const int tid = threadIdx.x;
  if (tid < 192) clfs[tid / 24][tid % 24] = clfg[tid];
  __syncthreads();

  const int co = tid & 127;
  const int kh = tid >> 7;              // 0..1
  float wo_r[24];
  #pragma unroll
  for (int c = 0; c < 24; ++c) wo_r[c] = Wo[(size_t)co * HD + e*24 + c];
  #pragma unroll
  for (int t = 0; t < 4; ++t) {
    const int g = kh * 4 + t;
    float s = 0.f;
    #pragma unroll
    for (int c = 0; c < 24; ++c) s = fmaf(wo_r[c], clfs[g][c], s);
    projb[((size_t)e * 8 + g) * 128 + co] = s;
  }
}

// ---------------- Kernel 3: output via proj lookup; per (b,f1,rowpair) ----------------
__global__ __launch_bounds__(256) void out_k(
    const float* __restrict__ qbuf, const float* __restrict__ bo,
    float* __restrict__ out)
{
  const int bid = blockIdx.x;           // (b*2+f1)*14 + rp
  const int b   = bid / 28;
  const int rem = bid % 28;
  const int f1  = rem / 14;
  const int rp  = rem % 14;
  const int n0  = rp * 112;             // slab-local pixel base (2 rows)

  __shared__ float  proj_l[4096];       // [k][co], k = e*8+g
  __shared__ float4 s_l4[112];          // s per pixel, 4 heads
  __shared__ unsigned int g_l[112];     // packed g per pixel (8 bits/head)
  __shared__ float  out_l[56 * 132];    // [pxl][co], padded

  const int tid = threadIdx.x;

  {
    const float4* pg = reinterpret_cast<const float4*>(
        qbuf + ((size_t)b * 96 + 3 + f1*3) * SP);
    float4* pl = reinterpret_cast<float4*>(proj_l);
    #pragma unroll
    for (int r = 0; r < 4; ++r) pl[tid + r * 256] = pg[tid + r * 256];
  }
  for (int i = tid; i < 112; i += 256) {
    float4 sv; unsigned int gp = 0;
    #pragma unroll
    for (int e = 0; e < 4; ++e) {
      const float* sp = qbuf + ((size_t)(b*4 + e) * 24) * SP + (size_t)(f1*28) * ROW;
      const float sval = sp[n0 + i];
      const unsigned int gv = reinterpret_cast<const unsigned int*>(sp + SP)[n0 + i];
      if (e == 0) sv.x = sval; else if (e == 1) sv.y = sval;
      else if (e == 2) sv.z = sval; else sv.w = sval;
      gp |= (gv & 7u) << (8 * e);
    }
    s_l4[i] = sv; g_l[i] = gp;
  }
  __syncthreads();

  const int cq  = tid & 31;             // co quad: co = cq*4..cq*4+3
  const int sub = tid >> 5;             // 0..7, 7 px each per chunk
  const float4 bo4 = *reinterpret_cast<const float4*>(bo + cq * 4);
  const float4* pl4 = reinterpret_cast<const float4*>(proj_l);

  for (int chunk = 0; chunk < 2; ++chunk) {
    const int pbase = chunk * 56;
    #pragma unroll
    for (int i = 0; i < 7; ++i) {
      const int pxl = sub * 7 + i;      // 0..55
      const int px  = pbase + pxl;
      const float4 sv = s_l4[px];
      const unsigned int gp = g_l[px];
      float4 acc = bo4;
      {
        const float4 p = pl4[(0*8 + (gp        & 7u)) * 32 + cq];
        acc.x = fmaf(sv.x, p.x, acc.x); acc.y = fmaf(sv.x, p.y, acc.y);
        acc.z = fmaf(sv.x, p.z, acc.z); acc.w = fmaf(sv.x, p.w, acc.w);
      }
      {
        const float4 p = pl4[(1*8 + ((gp >> 8) & 7u)) * 32 + cq];
        acc.x = fmaf(sv.y, p.x, acc.x); acc.y = fmaf(sv.y, p.y, acc.y);
        acc.z = fmaf(sv.y, p.z, acc.z); acc.w = fmaf(sv.y, p.w, acc.w);
      }
      {
        const float4 p = pl4[(2*8 + ((gp >> 16) & 7u)) * 32 + cq];
        acc.x = fmaf(sv.z, p.x, acc.x); acc.y = fmaf(sv.z, p.y, acc.y);
        acc.z = fmaf(sv.z, p.z, acc.z); acc.w = fmaf(sv.z, p.w, acc.w);
      }
      {
        const float4 p = pl4[(3*8 + ((gp >> 24) & 7u)) * 32 + cq];
        acc.x = fmaf(sv.w, p.x, acc.x); acc.y = fmaf(sv.w, p.y, acc.y);
        acc.z = fmaf(sv.w, p.z, acc.z); acc.w = fmaf(sv.w, p.w, acc.w);
      }
      *reinterpret_cast<float4*>(&out_l[pxl * 132 + cq * 4]) = acc;
    }
    __syncthreads();
    // coalesced writeback: 128 co x 56 px
    for (int t = tid; t < 128 * 56; t += 256) {
      const int co = t / 56, pxl = t - co * 56;
      out[((size_t)b * 128 + co) * SP + (size_t)f1 * SLAB + n0 + pbase + pxl] =
          out_l[pxl * 132 + co];
    }
    __syncthreads();
  }
}

extern "C" void kernel_launch(void* const* d_in, const int* in_sizes, int n_in,
                              void* d_out, int out_size, void* d_ws, size_t ws_size,
                              hipStream_t stream) {
  const float* x  = (const float*)d_in[0];
  const float* Wc = (const float*)d_in[1];
  const float* bc = (const float*)d_in[2];
  const float* Wp = (const float*)d_in[3];
  const float* bp = (const float*)d_in[4];
  const float* sa = (const float*)d_in[5];
  const float* sb = (const float*)d_in[6];
  const float* Wo = (const float*)d_in[7];
  const float* bo = (const float*)d_in[8];
  float* out  = (float*)d_out;
  float* qbuf = (float*)d_ws;   // 77.1 MB; s/g/clf/proj reuse dead q channels
  float* vbuf = out;            // value scratch inside d_out; overwritten by out_k

  qv_conv<<<dim3(64 * 49), dim3(256), 0, stream>>>(x, Wc, bc, Wp, bp, qbuf, vbuf);
  cluster_k<<<dim3(512), dim3(512), 0, stream>>>(qbuf, vbuf, sa, sb);
  proj_k<<<dim3(512), dim3(256), 0, stream>>>(qbuf, Wo);
  out_k<<<dim3(1792), dim3(256), 0, stream>>>(qbuf, bo, out);
}

// Round 8
// 264.627 us; speedup vs baseline: 2.6556x; 1.0046x over previous
//
#include <hip/hip_runtime.h>
#include <math.h>

#define CIN 128
#define HD  96
#define SP  3136   // 56*56
#define ROW 56
#define SLAB 1568  // 28*56

// ---------------- Kernel 0: transpose W into Wt[c][o] (o<96: Wc, else Wp) ----------------
__global__ __launch_bounds__(256) void wt_k(
    const float* __restrict__ Wc, const float* __restrict__ Wp,
    float* __restrict__ Wt)
{
  const int idx = blockIdx.x * 256 + threadIdx.x;   // 0..24575
  if (idx >= 128 * 192) return;
  const int c = idx / 192, o = idx - c * 192;
  Wt[idx] = (o < 96) ? Wc[(size_t)o * CIN + c] : Wp[(size_t)(o - 96) * CIN + c];
}

// ---------------- Kernel 1: q/value 1x1 conv — LDS-free, W via scalar loads ----------------
// 4 waves/block; wave w owns outputs [w*48, w*48+48); lane = spatial column.
__global__ __launch_bounds__(256) void qv_conv(
    const float* __restrict__ x, const float* __restrict__ Wt,
    const float* __restrict__ bc, const float* __restrict__ bp,
    float* __restrict__ qbuf, float* __restrict__ vbuf)
{
  const int st = blockIdx.x % 49;
  const int b  = blockIdx.x / 49;
  const int tid = threadIdx.x;
  const int lane = tid & 63;
  const int wq = __builtin_amdgcn_readfirstlane(tid >> 6);   // 0..3, wave-uniform
  const float* xg = x + (size_t)b * CIN * SP + st * 64 + lane;
  const float* wbase = Wt + wq * 48;

  float acc[48];
  #pragma unroll
  for (int i = 0; i < 48; ++i) acc[i] = 0.f;

  #pragma unroll 2
  for (int c = 0; c < CIN; ++c) {
    const float xv = xg[(size_t)c * SP];                     // coalesced VGPR load
    const float4* wr = reinterpret_cast<const float4*>(wbase + (size_t)c * 192);
    #pragma unroll
    for (int j = 0; j < 12; ++j) {
      const float4 w4 = wr[j];                               // uniform -> s_load_dwordx4
      acc[j*4+0] = fmaf(w4.x, xv, acc[j*4+0]);
      acc[j*4+1] = fmaf(w4.y, xv, acc[j*4+1]);
      acc[j*4+2] = fmaf(w4.z, xv, acc[j*4+2]);
      acc[j*4+3] = fmaf(w4.w, xv, acc[j*4+3]);
    }
  }

  if (wq < 2) {          // q waves: outputs 0..95
    const int o0 = wq * 48;
    #pragma unroll
    for (int i = 0; i < 48; ++i) {
      const int o = o0 + i;
      qbuf[((size_t)b * 96 + o) * SP + st * 64 + lane] = acc[i] + bc[o];
    }
  } else {               // v waves: outputs 96..191 -> v channels 0..95
    const int o0 = wq * 48 - 96;
    #pragma unroll
    for (int i = 0; i < 48; ++i) {
      const int o = o0 + i;
      vbuf[((size_t)b * 96 + o) * SP + st * 64 + lane] = acc[i] + bp[o];
    }
  }
}

// ---------------- Kernel 2: clustering per (b,e,f1); exports s/g/clf into dead q ----------------
__global__ __launch_bounds__(512, 4) void cluster_k(
    float* qbuf, const float* __restrict__ vbuf,
    const float* __restrict__ alpha_p, const float* __restrict__ beta_p)
{
  const int blk = blockIdx.x;              // (b*4+e)*2 + f1
  const int f1  = blk & 1;
  const int be  = blk >> 1;
  const size_t base = (size_t)be * 24 * SP + (size_t)(f1 * 28) * ROW;
  float* qp = qbuf + base;
  const float* vp = vbuf + base;

  __shared__ double cnd[24][8];
  __shared__ float  sbest[SLAB];
  __shared__ unsigned char ibest[SLAB];
  __shared__ float  clr[8][24];
  __shared__ float  vcr[8][24];
  __shared__ float  dnf[8];

  const int tid  = threadIdx.x;
  const int wid  = tid >> 6;
  const int lane = tid & 63;

  for (int c = wid; c < 24; c += 8) {
    const float* src = qp + (size_t)c * SP;
    double b0=0,b1=0,b2=0,b3=0,b4=0,b5=0,b6=0,b7=0;
    for (int n = lane; n < SLAB; n += 64) {
      const int w = n / 56, h = n - w * 56;
      const int hf = (h >= 28) ? (h - 28) : h;
      const int g  = ((h >= 28) ? 4 : 0) + ((w >= 14) ? 2 : 0) + ((hf >= 14) ? 1 : 0);
      const double val = (double)src[n];
      b0 += (g==0)?val:0.0; b1 += (g==1)?val:0.0;
      b2 += (g==2)?val:0.0; b3 += (g==3)?val:0.0;
      b4 += (g==4)?val:0.0; b5 += (g==5)?val:0.0;
      b6 += (g==6)?val:0.0; b7 += (g==7)?val:0.0;
    }
    #pragma unroll
    for (int m = 32; m >= 1; m >>= 1) {
      b0 += __shfl_xor(b0,m); b1 += __shfl_xor(b1,m);
      b2 += __shfl_xor(b2,m); b3 += __shfl_xor(b3,m);
      b4 += __shfl_xor(b4,m); b5 += __shfl_xor(b5,m);
      b6 += __shfl_xor(b6,m); b7 += __shfl_xor(b7,m);
    }
    if (lane == 0) {
      cnd[c][0]=b0*(1.0/196.0); cnd[c][1]=b1*(1.0/196.0);
      cnd[c][2]=b2*(1.0/196.0); cnd[c][3]=b3*(1.0/196.0);
      cnd[c][4]=b4*(1.0/196.0); cnd[c][5]=b5*(1.0/196.0);
      cnd[c][6]=b6*(1.0/196.0); cnd[c][7]=b7*(1.0/196.0);
    }
  }
  __syncthreads();
  if (tid < 8) {
    double s = 0.0;
    #pragma unroll
    for (int c = 0; c < 24; ++c) { double t = cnd[c][tid]; s += t * t; }
    const double inv = 1.0 / fmax(sqrt(s), 1e-12);
    #pragma unroll
    for (int c = 0; c < 24; ++c) cnd[c][tid] *= inv;
  }
  __syncthreads();

  const double alpha = (double)alpha_p[0];
  const double beta  = (double)beta_p[0];

  for (int n0 = tid; n0 < SLAB; n0 += 512) {
    const int h  = n0 % 56;
    const int gb = (h >= 28) ? 4 : 0;
    double z0=0,z1=0,z2=0,z3=0,nrm=0;
    for (int c = 0; c < 24; ++c) {
      const double qv = (double)qp[(size_t)c * SP + n0];
      z0 += cnd[c][gb+0]*qv; z1 += cnd[c][gb+1]*qv;
      z2 += cnd[c][gb+2]*qv; z3 += cnd[c][gb+3]*qv;
      nrm += qv*qv;
    }
    const double inv = 1.0 / fmax(sqrt(nrm), 1e-12);
    const double v0 = beta + alpha * (z0 * inv);
    const double v1 = beta + alpha * (z1 * inv);
    const double v2 = beta + alpha * (z2 * inv);
    const double v3 = beta + alpha * (z3 * inv);
    double zb = v0; int bi = 0;
    if (v1 > zb) { zb = v1; bi = 1; }
    if (v2 > zb) { zb = v2; bi = 2; }
    if (v3 > zb) { zb = v3; bi = 3; }
    sbest[n0] = (float)(1.0 / (1.0 + exp(-zb)));
    ibest[n0] = (unsigned char)(gb + bi);
  }
  __syncthreads();

  for (int c = wid; c < 24; c += 8) {
    const float* vsrc = vp + (size_t)c * SP;
    float cl0=0,cl1=0,cl2=0,cl3=0,cl4=0,cl5=0,cl6=0,cl7=0;
    float vc0=0,vc1=0,vc2=0,vc3=0,vc4=0,vc5=0,vc6=0,vc7=0;
    float dn0=0,dn1=0,dn2=0,dn3=0,dn4=0,dn5=0,dn6=0,dn7=0;
    for (int n = lane; n < SLAB; n += 64) {
      const int w = n / 56, h = n - w * 56;
      const int hf = (h >= 28) ? (h - 28) : h;
      const int fb = (h >= 28) ? 4 : 0;
      const float v = vsrc[n];
      const float s = sbest[n];
      const int gi = ibest[n];
      const int gm = fb + ((w >= 14) ? 2 : 0) + ((hf >= 14) ? 1 : 0);
      const float sv = s * v;
      cl0 += (gi==0)?sv:0.f; cl1 += (gi==1)?sv:0.f;
      cl2 += (gi==2)?sv:0.f; cl3 += (gi==3)?sv:0.f;
      cl4 += (gi==4)?sv:0.f; cl5 += (gi==5)?sv:0.f;
      cl6 += (gi==6)?sv:0.f; cl7 += (gi==7)?sv:0.f;
      vc0 += (gm==0)?v:0.f;  vc1 += (gm==1)?v:0.f;
      vc2 += (gm==2)?v:0.f;  vc3 += (gm==3)?v:0.f;
      vc4 += (gm==4)?v:0.f;  vc5 += (gm==5)?v:0.f;
      vc6 += (gm==6)?v:0.f;  vc7 += (gm==7)?v:0.f;
      dn0 += (gi==0)?s:0.f;  dn1 += (gi==1)?s:0.f;
      dn2 += (gi==2)?s:0.f;  dn3 += (gi==3)?s:0.f;
      dn4 += (gi==4)?s:0.f;  dn5 += (gi==5)?s:0.f;
      dn6 += (gi==6)?s:0.f;  dn7 += (gi==7)?s:0.f;
    }
    #pragma unroll
    for (int m = 32; m >= 1; m >>= 1) {
      cl0 += __shfl_xor(cl0,m); cl1 += __shfl_xor(cl1,m);
      cl2 += __shfl_xor(cl2,m); cl3 += __shfl_xor(cl3,m);
      cl4 += __shfl_xor(cl4,m); cl5 += __shfl_xor(cl5,m);
      cl6 += __shfl_xor(cl6,m); cl7 += __shfl_xor(cl7,m);
      vc0 += __shfl_xor(vc0,m); vc1 += __shfl_xor(vc1,m);
      vc2 += __shfl_xor(vc2,m); vc3 += __shfl_xor(vc3,m);
      vc4 += __shfl_xor(vc4,m); vc5 += __shfl_xor(vc5,m);
      vc6 += __shfl_xor(vc6,m); vc7 += __shfl_xor(vc7,m);
      dn0 += __shfl_xor(dn0,m); dn1 += __shfl_xor(dn1,m);
      dn2 += __shfl_xor(dn2,m); dn3 += __shfl_xor(dn3,m);
      dn4 += __shfl_xor(dn4,m); dn5 += __shfl_xor(dn5,m);
      dn6 += __shfl_xor(dn6,m); dn7 += __shfl_xor(dn7,m);
    }
    if (lane == 0) {
      clr[0][c]=cl0; clr[1][c]=cl1; clr[2][c]=cl2; clr[3][c]=cl3;
      clr[4][c]=cl4; clr[5][c]=cl5; clr[6][c]=cl6; clr[7][c]=cl7;
      vcr[0][c]=vc0*(1.f/196.f); vcr[1][c]=vc1*(1.f/196.f);
      vcr[2][c]=vc2*(1.f/196.f); vcr[3][c]=vc3*(1.f/196.f);
      vcr[4][c]=vc4*(1.f/196.f); vcr[5][c]=vc5*(1.f/196.f);
      vcr[6][c]=vc6*(1.f/196.f); vcr[7][c]=vc7*(1.f/196.f);
      if (c == 0) {
        dnf[0]=dn0; dnf[1]=dn1; dnf[2]=dn2; dnf[3]=dn3;
        dnf[4]=dn4; dnf[5]=dn5; dnf[6]=dn6; dnf[7]=dn7;
      }
    }
  }
  __syncthreads();

  if (tid < 192) {
    const int g = tid / 24, c = tid - g * 24;
    qp[2 * (size_t)SP + tid] = (clr[g][c] + vcr[g][c]) / (dnf[g] + 1.0f);
  }
  for (int i = tid; i < SLAB; i += 512) {
    qp[i] = sbest[i];
    reinterpret_cast<unsigned int*>(qp + SP)[i] = (unsigned int)ibest[i];
  }
}

// ---------------- Kernel 2b: proj[e*8+g][co] = Wo_e[co] . clf_e[g]  per (b,f1,e) ----------------
__global__ __launch_bounds__(256) void proj_k(
    float* qbuf, const float* __restrict__ Wo)
{
  const int bid = blockIdx.x;           // ((b*2+f1)*4 + e)
  const int e   = bid & 3;
  const int f1  = (bid >> 2) & 1;
  const int b   = bid >> 3;
  const float* clfg = qbuf + ((size_t)(b*4 + e) * 24 + 2) * SP + (size_t)(f1*28) * ROW;
  float* projb = qbuf + ((size_t)b * 96 + 3 + f1*3) * SP;

  __shared__ float clfs[8][24];
  const int tid = threadIdx.x;
  if (tid < 192) clfs[tid / 24][tid % 24] = clfg[tid];
  __syncthreads();

  const int co = tid & 127;
  const int kh = tid >> 7;
  float wo_r[24];
  #pragma unroll
  for (int c = 0; c < 24; ++c) wo_r[c] = Wo[(size_t)co * HD + e*24 + c];
  #pragma unroll
  for (int t = 0; t < 4; ++t) {
    const int g = kh * 4 + t;
    float s = 0.f;
    #pragma unroll
    for (int c = 0; c < 24; ++c) s = fmaf(wo_r[c], clfs[g][c], s);
    projb[((size_t)e * 8 + g) * 128 + co] = s;
  }
}

// ---------------- Kernel 3: output via proj lookup; per (b,f1,rowpair) ----------------
__global__ __launch_bounds__(256) void out_k(
    const float* __restrict__ qbuf, const float* __restrict__ bo,
    float* __restrict__ out)
{
  const int bid = blockIdx.x;           // (b*2+f1)*14 + rp
  const int b   = bid / 28;
  const int rem = bid % 28;
  const int f1  = rem / 14;
  const int rp  = rem % 14;
  const int n0  = rp * 112;

  __shared__ float  proj_l[4096];
  __shared__ float4 s_l4[112];
  __shared__ unsigned int g_l[112];
  __shared__ float  out_l[56 * 132];

  const int tid = threadIdx.x;

  {
    const float4* pg = reinterpret_cast<const float4*>(
        qbuf + ((size_t)b * 96 + 3 + f1*3) * SP);
    float4* pl = reinterpret_cast<float4*>(proj_l);
    #pragma unroll
    for (int r = 0; r < 4; ++r) pl[tid + r * 256] = pg[tid + r * 256];
  }
  for (int i = tid; i < 112; i += 256) {
    float4 sv; unsigned int gp = 0;
    #pragma unroll
    for (int e = 0; e < 4; ++e) {
      const float* sp = qbuf + ((size_t)(b*4 + e) * 24) * SP + (size_t)(f1*28) * ROW;
      const float sval = sp[n0 + i];
      const unsigned int gv = reinterpret_cast<const unsigned int*>(sp + SP)[n0 + i];
      if (e == 0) sv.x = sval; else if (e == 1) sv.y = sval;
      else if (e == 2) sv.z = sval; else sv.w = sval;
      gp |= (gv & 7u) << (8 * e);
    }
    s_l4[i] = sv; g_l[i] = gp;
  }
  __syncthreads();

  const int cq  = tid & 31;
  const int sub = tid >> 5;
  const float4 bo4 = *reinterpret_cast<const float4*>(bo + cq * 4);
  const float4* pl4 = reinterpret_cast<const float4*>(proj_l);

  for (int chunk = 0; chunk < 2; ++chunk) {
    const int pbase = chunk * 56;
    #pragma unroll
    for (int i = 0; i < 7; ++i) {
      const int pxl = sub * 7 + i;
      const int px  = pbase + pxl;
      const float4 sv = s_l4[px];
      const unsigned int gp = g_l[px];
      float4 acc = bo4;
      {
        const float4 p = pl4[(0*8 + (gp        & 7u)) * 32 + cq];
        acc.x = fmaf(sv.x, p.x, acc.x); acc.y = fmaf(sv.x, p.y, acc.y);
        acc.z = fmaf(sv.x, p.z, acc.z); acc.w = fmaf(sv.x, p.w, acc.w);
      }
      {
        const float4 p = pl4[(1*8 + ((gp >> 8) & 7u)) * 32 + cq];
        acc.x = fmaf(sv.y, p.x, acc.x); acc.y = fmaf(sv.y, p.y, acc.y);
        acc.z = fmaf(sv.y, p.z, acc.z); acc.w = fmaf(sv.y, p.w, acc.w);
      }
      {
        const float4 p = pl4[(2*8 + ((gp >> 16) & 7u)) * 32 + cq];
        acc.x = fmaf(sv.z, p.x, acc.x); acc.y = fmaf(sv.z, p.y, acc.y);
        acc.z = fmaf(sv.z, p.z, acc.z); acc.w = fmaf(sv.z, p.w, acc.w);
      }
      {
        const float4 p = pl4[(3*8 + ((gp >> 24) & 7u)) * 32 + cq];
        acc.x = fmaf(sv.w, p.x, acc.x); acc.y = fmaf(sv.w, p.y, acc.y);
        acc.z = fmaf(sv.w, p.z, acc.z); acc.w = fmaf(sv.w, p.w, acc.w);
      }
      *reinterpret_cast<float4*>(&out_l[pxl * 132 + cq * 4]) = acc;
    }
    __syncthreads();
    for (int t = tid; t < 128 * 56; t += 256) {
      const int co = t / 56, pxl = t - co * 56;
      out[((size_t)b * 128 + co) * SP + (size_t)f1 * SLAB + n0 + pbase + pxl] =
          out_l[pxl * 132 + co];
    }
    __syncthreads();
  }
}

extern "C" void kernel_launch(void* const* d_in, const int* in_sizes, int n_in,
                              void* d_out, int out_size, void* d_ws, size_t ws_size,
                              hipStream_t stream) {
  const float* x  = (const float*)d_in[0];
  const float* Wc = (const float*)d_in[1];
  const float* bc = (const float*)d_in[2];
  const float* Wp = (const float*)d_in[3];
  const float* bp = (const float*)d_in[4];
  const float* sa = (const float*)d_in[5];
  const float* sb = (const float*)d_in[6];
  const float* Wo = (const float*)d_in[7];
  const float* bo = (const float*)d_in[8];
  float* out  = (float*)d_out;
  float* qbuf = (float*)d_ws;                       // 77.1 MB
  float* vbuf = out;                                // v scratch in d_out, overwritten by out_k
  float* wt   = out + (size_t)64 * 96 * SP;         // 98 KB in dead d_out space past vbuf

  wt_k<<<dim3(96), dim3(256), 0, stream>>>(Wc, Wp, wt);
  qv_conv<<<dim3(64 * 49), dim3(256), 0, stream>>>(x, wt, bc, bp, qbuf, vbuf);
  cluster_k<<<dim3(512), dim3(512), 0, stream>>>(qbuf, vbuf, sa, sb);
  proj_k<<<dim3(512), dim3(256), 0, stream>>>(qbuf, Wo);
  out_k<<<dim3(1792), dim3(256), 0, stream>>>(qbuf, bo, out);
}